// Round 2
// baseline (389.575 us; speedup 1.0000x reference)
//
#include <hip/hip_runtime.h>
#include <cstddef>

// Problem constants
static constexpr int kB    = 256;   // batch
static constexpr int kS    = 196;   // att size (sequence)
static constexpr int kRNN  = 1024;  // rnn size
static constexpr int kATTH = 512;   // att hidden size

__device__ __forceinline__ float fast_tanh(float x) {
    // tanh(x) = (e^{2x}-1)/(e^{2x}+1); clamp so __expf stays finite.
    x = fminf(12.0f, fmaxf(-12.0f, x));
    float e = __expf(2.0f * x);
    return __fdividef(e - 1.0f, e + 1.0f);
}

__device__ __forceinline__ float dot8t(const float4 p0, const float4 p1,
                                       const float4 ah0, const float4 ah1,
                                       const float4 wa0, const float4 wa1) {
    float r;
    r  = fast_tanh(p0.x + ah0.x) * wa0.x;
    r += fast_tanh(p0.y + ah0.y) * wa0.y;
    r += fast_tanh(p0.z + ah0.z) * wa0.z;
    r += fast_tanh(p0.w + ah0.w) * wa0.w;
    r += fast_tanh(p1.x + ah1.x) * wa1.x;
    r += fast_tanh(p1.y + ah1.y) * wa1.y;
    r += fast_tanh(p1.z + ah1.z) * wa1.z;
    r += fast_tanh(p1.w + ah1.w) * wa1.w;
    return r;
}

// Single fused kernel: one block per batch element b, 1024 threads = 16 waves.
// Phase 0: att_h[b,:] = W h_b + bias   (W is L2-resident, coalesced row loads)
// Stream : per s (waves split s):  score_s = dot(tanh(p+att_h), w_alpha);
//          e_s = exp(score_s + b_alpha - M)  with data-independent bound
//          M = sum|w_alpha| + |b_alpha|  (safe: |tanh|<=1), then
//          acc_d += e_s * att_feats[s,d], ssum += e_s.  No softmax barrier.
// Final  : cross-wave LDS reduce, out = acc / ssum.
__global__ __launch_bounds__(1024) void att_one(
    const float* __restrict__ h,
    const float* __restrict__ att_feats,
    const float* __restrict__ p_att,
    const float* __restrict__ w_h2att,
    const float* __restrict__ b_h2att,
    const float* __restrict__ w_alpha,
    const float* __restrict__ b_alpha,
    float* __restrict__ out) {
    const int b = blockIdx.x;
    const int tid = threadIdx.x;
    const int lane = tid & 63;
    const int wave = tid >> 6;  // 0..15

    __shared__ float sAttH[kATTH];
    __shared__ float4 sAcc[16][256];  // per-wave partial acc over RNN=1024
    __shared__ float sSum[16];

    const int col = lane << 3;  // 8 atth elements per lane
    const float* pbase = &p_att[(size_t)b * kS * kATTH + col];
    const float* abase = &att_feats[(size_t)b * kS * kRNN + (lane << 2)];

    // ---- Prefetch stream iteration s = wave BEFORE phase 0 (hides under GEMM).
    int s = wave;  // always < kS
    float4 p0, p1, v0, v1, v2, v3;
    {
        const float* p = pbase + (size_t)s * kATTH;
        p0 = *(const float4*)p;
        p1 = *(const float4*)(p + 4);
        const float* a = abase + (size_t)s * kRNN;
        v0 = *(const float4*)(a);
        v1 = *(const float4*)(a + 256);
        v2 = *(const float4*)(a + 512);
        v3 = *(const float4*)(a + 768);
    }

    // ---- Phase 0: att_h row for this b. Wave w computes rows a = 32w..32w+31.
    {
        const float* hb = &h[(size_t)b * kRNN];
        const int k0 = lane << 2;  // lane covers k0, k0+256, k0+512, k0+768
        const float4 h0 = *(const float4*)&hb[k0];
        const float4 h1 = *(const float4*)&hb[k0 + 256];
        const float4 h2 = *(const float4*)&hb[k0 + 512];
        const float4 h3 = *(const float4*)&hb[k0 + 768];
        const int abase0 = wave << 5;
#pragma unroll 2
        for (int r = 0; r < 32; ++r) {
            const int a = abase0 + r;
            const float* wr = &w_h2att[(size_t)a * kRNN + k0];
            const float4 x0 = *(const float4*)(wr);
            const float4 x1 = *(const float4*)(wr + 256);
            const float4 x2 = *(const float4*)(wr + 512);
            const float4 x3 = *(const float4*)(wr + 768);
            float d;
            d  = x0.x * h0.x + x0.y * h0.y + x0.z * h0.z + x0.w * h0.w;
            d += x1.x * h1.x + x1.y * h1.y + x1.z * h1.z + x1.w * h1.w;
            d += x2.x * h2.x + x2.y * h2.y + x2.z * h2.z + x2.w * h2.w;
            d += x3.x * h3.x + x3.y * h3.y + x3.z * h3.z + x3.w * h3.w;
#pragma unroll
            for (int off = 32; off > 0; off >>= 1) d += __shfl_xor(d, off, 64);
            if (lane == 0) sAttH[a] = d + b_h2att[a];
        }
    }
    __syncthreads();

    // ---- Per-lane constants for the stream
    const float4 ah0 = *(const float4*)&sAttH[col];
    const float4 ah1 = *(const float4*)&sAttH[col + 4];
    const float4 wa0 = *(const float4*)&w_alpha[col];
    const float4 wa1 = *(const float4*)&w_alpha[col + 4];
    const float balpha = b_alpha[0];

    // Data-independent score bound M = sum_a |w_alpha[a]| + |b_alpha|
    float sw = fabsf(wa0.x) + fabsf(wa0.y) + fabsf(wa0.z) + fabsf(wa0.w) +
               fabsf(wa1.x) + fabsf(wa1.y) + fabsf(wa1.z) + fabsf(wa1.w);
#pragma unroll
    for (int off = 32; off > 0; off >>= 1) sw += __shfl_xor(sw, off, 64);
    const float ebias = balpha - (sw + fabsf(balpha));  // score + ebias <= 0

    // ---- Fused stream: score -> e_s -> weighted accumulate, 2-stage pipeline
    float4 acc0 = {0.f, 0.f, 0.f, 0.f}, acc1 = {0.f, 0.f, 0.f, 0.f};
    float4 acc2 = {0.f, 0.f, 0.f, 0.f}, acc3 = {0.f, 0.f, 0.f, 0.f};
    float ssum = 0.f;
    while (true) {
        const int sn = s + 16;
        const bool more = sn < kS;  // wave-uniform
        float4 np0, np1, nv0, nv1, nv2, nv3;
        if (more) {
            const float* p = pbase + (size_t)sn * kATTH;
            np0 = *(const float4*)p;
            np1 = *(const float4*)(p + 4);
            const float* a = abase + (size_t)sn * kRNN;
            nv0 = *(const float4*)(a);
            nv1 = *(const float4*)(a + 256);
            nv2 = *(const float4*)(a + 512);
            nv3 = *(const float4*)(a + 768);
        }
        float r = dot8t(p0, p1, ah0, ah1, wa0, wa1);
#pragma unroll
        for (int off = 32; off > 0; off >>= 1) r += __shfl_xor(r, off, 64);
        const float e = __expf(r + ebias);
        acc0.x += e * v0.x; acc0.y += e * v0.y; acc0.z += e * v0.z; acc0.w += e * v0.w;
        acc1.x += e * v1.x; acc1.y += e * v1.y; acc1.z += e * v1.z; acc1.w += e * v1.w;
        acc2.x += e * v2.x; acc2.y += e * v2.y; acc2.z += e * v2.z; acc2.w += e * v2.w;
        acc3.x += e * v3.x; acc3.y += e * v3.y; acc3.z += e * v3.z; acc3.w += e * v3.w;
        ssum += e;
        if (!more) break;
        s = sn;
        p0 = np0; p1 = np1;
        v0 = nv0; v1 = nv1; v2 = nv2; v3 = nv3;
    }

    // ---- Cross-wave reduction: acc chunk j covers d = 256j + 4*lane
    sAcc[wave][(0 << 6) + lane] = acc0;
    sAcc[wave][(1 << 6) + lane] = acc1;
    sAcc[wave][(2 << 6) + lane] = acc2;
    sAcc[wave][(3 << 6) + lane] = acc3;
    if (lane == 0) sSum[wave] = ssum;
    __syncthreads();

    float tot = 0.f;
#pragma unroll
    for (int w = 0; w < 16; ++w) tot += sSum[w];
    const float inv = __fdividef(1.0f, tot);

    const float* sA = (const float*)sAcc;
    float o = 0.f;
#pragma unroll
    for (int w = 0; w < 16; ++w) o += sA[w * 1024 + tid];
    out[(size_t)b * kRNN + tid] = o * inv;
}

extern "C" void kernel_launch(void* const* d_in, const int* in_sizes, int n_in,
                              void* d_out, int out_size, void* d_ws, size_t ws_size,
                              hipStream_t stream) {
    const float* h         = (const float*)d_in[0];
    const float* att_feats = (const float*)d_in[1];
    const float* p_att     = (const float*)d_in[2];
    const float* w_h2att   = (const float*)d_in[3];
    const float* b_h2att   = (const float*)d_in[4];
    const float* w_alpha   = (const float*)d_in[5];
    const float* b_alpha   = (const float*)d_in[6];
    float* out = (float*)d_out;

    att_one<<<kB, 1024, 0, stream>>>(h, att_feats, p_att, w_h2att, b_h2att,
                                     w_alpha, b_alpha, out);
}